// Round 1
// baseline (81.678 us; speedup 1.0000x reference)
//
#include <hip/hip_runtime.h>
#include <math.h>

#define D 64
#define NC 8
#define FK 8
#define NMIN 1440
#define TWO_PI_F 6.28318530717958647692f

// ---------------------------------------------------------------------------
// Kernel 1: build per-minute Fourier table T[m][n][d] (1440 x 8 x 64 fp32).
// F(m,n,d) = a0[n,d] + sum_k cos(k*ang_m)*fa[n,k,d] + sin(k*ang_m)*fb[n,k,d]
// ang_m = m * 2pi/1439  (reference uses N_MINUTES-1).
// ---------------------------------------------------------------------------
__global__ __launch_bounds__(256) void build_table_kernel(
    const float* __restrict__ a0,
    const float* __restrict__ fa,
    const float* __restrict__ fb,
    float* __restrict__ T)
{
    const int m = blockIdx.x;        // minute 0..1439
    const int t = threadIdx.x;       // 256 threads: 4 n-slots x 64 d
    const int d  = t & (D - 1);
    const int n0 = t >> 6;           // 0..3
    const float angle = (float)m * (TWO_PI_F / (float)(NMIN - 1));
    float c[FK], s[FK];
#pragma unroll
    for (int k = 0; k < FK; ++k) {
        sincosf(angle * (float)(k + 1), &s[k], &c[k]);
    }
#pragma unroll
    for (int j = 0; j < 2; ++j) {
        const int n = n0 + 4 * j;
        float v = a0[n * D + d];
#pragma unroll
        for (int k = 0; k < FK; ++k) {
            v = fmaf(c[k], fa[(n * FK + k) * D + d], v);
            v = fmaf(s[k], fb[(n * FK + k) * D + d], v);
        }
        T[(m * NC + n) * D + d] = v;
    }
}

// ---------------------------------------------------------------------------
// Kernel 2: one item per thread.
//  - scores = emb . proto^T / tau  (512 FMA, proto loads are wave-uniform)
//  - softmax over 8
//  - gather T[m] (8x64 fp32, L2-resident) and mix with P     (512 FMA)
// ---------------------------------------------------------------------------
__global__ __launch_bounds__(256) void mix_kernel(
    const float* __restrict__ emb,
    const float* __restrict__ thetas,
    const float* __restrict__ proto,
    const float* __restrict__ T,
    float* __restrict__ out_emb,
    float* __restrict__ out_P,
    int B)
{
    const int b = blockIdx.x * 256 + threadIdx.x;
    if (b >= B) return;

    const float4* __restrict__ e4 = (const float4*)(emb + (size_t)b * D);
    const float4* __restrict__ p4 = (const float4*)proto;

    float sc[NC];
#pragma unroll
    for (int n = 0; n < NC; ++n) sc[n] = 0.0f;

#pragma unroll
    for (int i = 0; i < D / 4; ++i) {
        const float4 ev = e4[i];
#pragma unroll
        for (int n = 0; n < NC; ++n) {
            const float4 pv = p4[n * (D / 4) + i];   // uniform across lanes
            sc[n] = fmaf(ev.x, pv.x, sc[n]);
            sc[n] = fmaf(ev.y, pv.y, sc[n]);
            sc[n] = fmaf(ev.z, pv.z, sc[n]);
            sc[n] = fmaf(ev.w, pv.w, sc[n]);
        }
    }

    // softmax(scores / tau), tau = 0.2 -> *5
    float mx = -1e30f;
#pragma unroll
    for (int n = 0; n < NC; ++n) { sc[n] *= 5.0f; mx = fmaxf(mx, sc[n]); }
    float sum = 0.0f;
#pragma unroll
    for (int n = 0; n < NC; ++n) { sc[n] = __expf(sc[n] - mx); sum += sc[n]; }
    const float inv = 1.0f / sum;
#pragma unroll
    for (int n = 0; n < NC; ++n) sc[n] *= inv;

    // minute bucket, replicating reference op order: (theta / 2pi) * 1440 -> int
    const float th = thetas[b];
    int m = (int)((th / TWO_PI_F) * (float)NMIN);
    m = m < 0 ? 0 : (m > NMIN - 1 ? NMIN - 1 : m);

    const float4* __restrict__ t4 = (const float4*)(T + (size_t)m * NC * D);
    float4 acc[D / 4];
#pragma unroll
    for (int i = 0; i < D / 4; ++i) acc[i] = make_float4(0.f, 0.f, 0.f, 0.f);
#pragma unroll
    for (int n = 0; n < NC; ++n) {
        const float pw = sc[n];
#pragma unroll
        for (int i = 0; i < D / 4; ++i) {
            const float4 tv = t4[n * (D / 4) + i];
            acc[i].x = fmaf(pw, tv.x, acc[i].x);
            acc[i].y = fmaf(pw, tv.y, acc[i].y);
            acc[i].z = fmaf(pw, tv.z, acc[i].z);
            acc[i].w = fmaf(pw, tv.w, acc[i].w);
        }
    }

    float4* o4 = (float4*)(out_emb + (size_t)b * D);
#pragma unroll
    for (int i = 0; i < D / 4; ++i) o4[i] = acc[i];

    float4* op = (float4*)(out_P + (size_t)b * NC);
    op[0] = make_float4(sc[0], sc[1], sc[2], sc[3]);
    op[1] = make_float4(sc[4], sc[5], sc[6], sc[7]);
}

// ---------------------------------------------------------------------------
// Fallback (only if ws_size < 3 MB): fully fused, coefficients staged in LDS.
// ---------------------------------------------------------------------------
__global__ __launch_bounds__(256) void fused_fallback(
    const float* __restrict__ emb,
    const float* __restrict__ thetas,
    const float* __restrict__ proto,
    const float* __restrict__ a0,
    const float* __restrict__ fa,
    const float* __restrict__ fb,
    float* __restrict__ out_emb,
    float* __restrict__ out_P,
    int B)
{
    __shared__ float sp[NC * D];
    __shared__ float sa0[NC * D];
    __shared__ float sfa[NC * FK * D];
    __shared__ float sfb[NC * FK * D];
    for (int i = threadIdx.x; i < NC * D; i += 256) { sp[i] = proto[i]; sa0[i] = a0[i]; }
    for (int i = threadIdx.x; i < NC * FK * D; i += 256) { sfa[i] = fa[i]; sfb[i] = fb[i]; }
    __syncthreads();

    const int b = blockIdx.x * 256 + threadIdx.x;
    if (b >= B) return;

    const float4* __restrict__ e4  = (const float4*)(emb + (size_t)b * D);
    const float4* sp4  = (const float4*)sp;
    const float4* sa04 = (const float4*)sa0;
    const float4* sfa4 = (const float4*)sfa;
    const float4* sfb4 = (const float4*)sfb;

    float sc[NC];
#pragma unroll
    for (int n = 0; n < NC; ++n) sc[n] = 0.0f;
#pragma unroll
    for (int i = 0; i < D / 4; ++i) {
        const float4 ev = e4[i];
#pragma unroll
        for (int n = 0; n < NC; ++n) {
            const float4 pv = sp4[n * (D / 4) + i];
            sc[n] = fmaf(ev.x, pv.x, sc[n]);
            sc[n] = fmaf(ev.y, pv.y, sc[n]);
            sc[n] = fmaf(ev.z, pv.z, sc[n]);
            sc[n] = fmaf(ev.w, pv.w, sc[n]);
        }
    }
    float mx = -1e30f;
#pragma unroll
    for (int n = 0; n < NC; ++n) { sc[n] *= 5.0f; mx = fmaxf(mx, sc[n]); }
    float sum = 0.0f;
#pragma unroll
    for (int n = 0; n < NC; ++n) { sc[n] = __expf(sc[n] - mx); sum += sc[n]; }
    const float inv = 1.0f / sum;
#pragma unroll
    for (int n = 0; n < NC; ++n) sc[n] *= inv;

    const float th = thetas[b];
    int m = (int)((th / TWO_PI_F) * (float)NMIN);
    m = m < 0 ? 0 : (m > NMIN - 1 ? NMIN - 1 : m);
    const float angle = (float)m * (TWO_PI_F / (float)(NMIN - 1));
    float c[FK], s[FK];
#pragma unroll
    for (int k = 0; k < FK; ++k) sincosf(angle * (float)(k + 1), &s[k], &c[k]);

    float4 acc[D / 4];
#pragma unroll
    for (int i = 0; i < D / 4; ++i) acc[i] = make_float4(0.f, 0.f, 0.f, 0.f);
#pragma unroll
    for (int n = 0; n < NC; ++n) {
        const float pw = sc[n];
#pragma unroll
        for (int i = 0; i < D / 4; ++i) {
            float4 v = sa04[n * (D / 4) + i];
#pragma unroll
            for (int k = 0; k < FK; ++k) {
                const float4 av = sfa4[(n * FK + k) * (D / 4) + i];
                const float4 bv = sfb4[(n * FK + k) * (D / 4) + i];
                v.x = fmaf(c[k], av.x, v.x); v.x = fmaf(s[k], bv.x, v.x);
                v.y = fmaf(c[k], av.y, v.y); v.y = fmaf(s[k], bv.y, v.y);
                v.z = fmaf(c[k], av.z, v.z); v.z = fmaf(s[k], bv.z, v.z);
                v.w = fmaf(c[k], av.w, v.w); v.w = fmaf(s[k], bv.w, v.w);
            }
            acc[i].x = fmaf(pw, v.x, acc[i].x);
            acc[i].y = fmaf(pw, v.y, acc[i].y);
            acc[i].z = fmaf(pw, v.z, acc[i].z);
            acc[i].w = fmaf(pw, v.w, acc[i].w);
        }
    }
    float4* o4 = (float4*)(out_emb + (size_t)b * D);
#pragma unroll
    for (int i = 0; i < D / 4; ++i) o4[i] = acc[i];
    float4* op = (float4*)(out_P + (size_t)b * NC);
    op[0] = make_float4(sc[0], sc[1], sc[2], sc[3]);
    op[1] = make_float4(sc[4], sc[5], sc[6], sc[7]);
}

extern "C" void kernel_launch(void* const* d_in, const int* in_sizes, int n_in,
                              void* d_out, int out_size, void* d_ws, size_t ws_size,
                              hipStream_t stream)
{
    const float* emb    = (const float*)d_in[0];
    const float* thetas = (const float*)d_in[1];
    const float* proto  = (const float*)d_in[2];
    const float* a0     = (const float*)d_in[3];
    const float* fa     = (const float*)d_in[4];
    const float* fb     = (const float*)d_in[5];

    const int B = in_sizes[0] / D;           // 131072
    float* out_emb = (float*)d_out;
    float* out_P   = (float*)d_out + (size_t)B * D;

    const size_t table_bytes = (size_t)NMIN * NC * D * sizeof(float); // ~2.95 MB
    const int blocks = (B + 255) / 256;

    if (ws_size >= table_bytes) {
        float* T = (float*)d_ws;
        build_table_kernel<<<NMIN, 256, 0, stream>>>(a0, fa, fb, T);
        mix_kernel<<<blocks, 256, 0, stream>>>(emb, thetas, proto, T, out_emb, out_P, B);
    } else {
        fused_fallback<<<blocks, 256, 0, stream>>>(emb, thetas, proto, a0, fa, fb,
                                                   out_emb, out_P, B);
    }
}

// Round 4
// 35.203 us; speedup vs baseline: 2.3202x; 2.3202x over previous
//
#include <hip/hip_runtime.h>
#include <math.h>

#define D 64
#define NC 8
#define FK 8
#define NMIN 1440
#define TWO_PI_F 6.28318530717958647692f

// ---------------------------------------------------------------------------
// Kernel 1: build per-minute Fourier table T[m][n][d] (1440 x 8 x 64 fp32).
// F(m,n,d) = a0[n,d] + sum_k cos(k*ang_m)*fa[n,k,d] + sin(k*ang_m)*fb[n,k,d]
// ang_m = m * 2pi/1439  (reference uses N_MINUTES-1).
// ---------------------------------------------------------------------------
__global__ __launch_bounds__(256) void build_table_kernel(
    const float* __restrict__ a0,
    const float* __restrict__ fa,
    const float* __restrict__ fb,
    float* __restrict__ T)
{
    const int m = blockIdx.x;        // minute 0..1439
    const int t = threadIdx.x;       // 256 threads: 4 n-slots x 64 d
    const int d  = t & (D - 1);
    const int n0 = t >> 6;           // 0..3
    const float angle = (float)m * (TWO_PI_F / (float)(NMIN - 1));
    float c[FK], s[FK];
#pragma unroll
    for (int k = 0; k < FK; ++k) {
        sincosf(angle * (float)(k + 1), &s[k], &c[k]);
    }
#pragma unroll
    for (int j = 0; j < 2; ++j) {
        const int n = n0 + 4 * j;
        float v = a0[n * D + d];
#pragma unroll
        for (int k = 0; k < FK; ++k) {
            v = fmaf(c[k], fa[(n * FK + k) * D + d], v);
            v = fmaf(s[k], fb[(n * FK + k) * D + d], v);
        }
        T[(m * NC + n) * D + d] = v;
    }
}

// ---------------------------------------------------------------------------
// Kernel 2: 16 lanes per item. Lane i owns float4 d-slice i (d = 4i..4i+3).
//  - emb read:   lane i loads emb[b][4i..4i+3]        -> 1KB/wave contiguous
//  - scores:     per-lane partial dot, shfl_xor reduce over the 16-lane group
//  - softmax(8)  computed redundantly in all 16 lanes (registers only)
//  - T gather:   lane i loads T[m][n][4i..4i+3], n=0..7 -> 256B/row coalesced
//  - mix + write: coalesced float4 stores
// ---------------------------------------------------------------------------
__global__ __launch_bounds__(256) void mix_kernel16(
    const float* __restrict__ emb,
    const float* __restrict__ thetas,
    const float* __restrict__ proto,
    const float* __restrict__ T,
    float* __restrict__ out_emb,
    float* __restrict__ out_P,
    int B)
{
    const int t = blockIdx.x * 256 + threadIdx.x;
    const int b = t >> 4;            // item index
    const int i = t & 15;            // d-slice index (float4 granularity)
    if (b >= B) return;

    // --- load this lane's emb slice (coalesced) ---
    const float4 ev = ((const float4*)emb)[(size_t)b * (D / 4) + i];

    // --- partial scores: sc[n] = dot(ev, proto[n][slice i]) ---
    const float4* __restrict__ p4 = (const float4*)proto;
    float sc[NC];
#pragma unroll
    for (int n = 0; n < NC; ++n) {
        const float4 pv = p4[n * (D / 4) + i];   // 2KB total, L1-resident
        float v = ev.x * pv.x;
        v = fmaf(ev.y, pv.y, v);
        v = fmaf(ev.z, pv.z, v);
        v = fmaf(ev.w, pv.w, v);
        sc[n] = v;
    }

    // --- reduce each score across the 16-lane group ---
#pragma unroll
    for (int n = 0; n < NC; ++n) {
        float v = sc[n];
        v += __shfl_xor(v, 1);
        v += __shfl_xor(v, 2);
        v += __shfl_xor(v, 4);
        v += __shfl_xor(v, 8);
        sc[n] = v;
    }

    // --- softmax(scores / tau), tau = 0.2 -> *5 (all lanes, registers only) ---
    float mx = -1e30f;
#pragma unroll
    for (int n = 0; n < NC; ++n) { sc[n] *= 5.0f; mx = fmaxf(mx, sc[n]); }
    float sum = 0.0f;
#pragma unroll
    for (int n = 0; n < NC; ++n) { sc[n] = __expf(sc[n] - mx); sum += sc[n]; }
    const float inv = 1.0f / sum;
#pragma unroll
    for (int n = 0; n < NC; ++n) sc[n] *= inv;

    // --- minute bucket (same op order as reference) ---
    const float th = thetas[b];                  // same addr across group -> bcast
    int m = (int)((th / TWO_PI_F) * (float)NMIN);
    m = m < 0 ? 0 : (m > NMIN - 1 ? NMIN - 1 : m);

    // --- gather T[m] rows (coalesced 256B per n) and mix ---
    const float4* __restrict__ t4 = (const float4*)(T + (size_t)m * NC * D);
    float4 acc = make_float4(0.f, 0.f, 0.f, 0.f);
#pragma unroll
    for (int n = 0; n < NC; ++n) {
        const float4 tv = t4[n * (D / 4) + i];
        const float pw = sc[n];
        acc.x = fmaf(pw, tv.x, acc.x);
        acc.y = fmaf(pw, tv.y, acc.y);
        acc.z = fmaf(pw, tv.z, acc.z);
        acc.w = fmaf(pw, tv.w, acc.w);
    }

    ((float4*)out_emb)[(size_t)b * (D / 4) + i] = acc;

    // --- P output: lanes 0 and 8 each write one float4 (compile-time select) ---
    if (i == 0) {
        ((float4*)out_P)[(size_t)b * 2 + 0] = make_float4(sc[0], sc[1], sc[2], sc[3]);
    } else if (i == 8) {
        ((float4*)out_P)[(size_t)b * 2 + 1] = make_float4(sc[4], sc[5], sc[6], sc[7]);
    }
}

// ---------------------------------------------------------------------------
// Fallback (only if ws_size < 3 MB): fully fused, coefficients staged in LDS.
// ---------------------------------------------------------------------------
__global__ __launch_bounds__(256) void fused_fallback(
    const float* __restrict__ emb,
    const float* __restrict__ thetas,
    const float* __restrict__ proto,
    const float* __restrict__ a0,
    const float* __restrict__ fa,
    const float* __restrict__ fb,
    float* __restrict__ out_emb,
    float* __restrict__ out_P,
    int B)
{
    __shared__ float sp[NC * D];
    __shared__ float sa0[NC * D];
    __shared__ float sfa[NC * FK * D];
    __shared__ float sfb[NC * FK * D];
    for (int i = threadIdx.x; i < NC * D; i += 256) { sp[i] = proto[i]; sa0[i] = a0[i]; }
    for (int i = threadIdx.x; i < NC * FK * D; i += 256) { sfa[i] = fa[i]; sfb[i] = fb[i]; }
    __syncthreads();

    const int b = blockIdx.x * 256 + threadIdx.x;
    if (b >= B) return;

    const float4* __restrict__ e4  = (const float4*)(emb + (size_t)b * D);
    const float4* sp4  = (const float4*)sp;
    const float4* sa04 = (const float4*)sa0;
    const float4* sfa4 = (const float4*)sfa;
    const float4* sfb4 = (const float4*)sfb;

    float sc[NC];
#pragma unroll
    for (int n = 0; n < NC; ++n) sc[n] = 0.0f;
#pragma unroll
    for (int i = 0; i < D / 4; ++i) {
        const float4 ev = e4[i];
#pragma unroll
        for (int n = 0; n < NC; ++n) {
            const float4 pv = sp4[n * (D / 4) + i];
            sc[n] = fmaf(ev.x, pv.x, sc[n]);
            sc[n] = fmaf(ev.y, pv.y, sc[n]);
            sc[n] = fmaf(ev.z, pv.z, sc[n]);
            sc[n] = fmaf(ev.w, pv.w, sc[n]);
        }
    }
    float mx = -1e30f;
#pragma unroll
    for (int n = 0; n < NC; ++n) { sc[n] *= 5.0f; mx = fmaxf(mx, sc[n]); }
    float sum = 0.0f;
#pragma unroll
    for (int n = 0; n < NC; ++n) { sc[n] = __expf(sc[n] - mx); sum += sc[n]; }
    const float inv = 1.0f / sum;
#pragma unroll
    for (int n = 0; n < NC; ++n) sc[n] *= inv;

    const float th = thetas[b];
    int m = (int)((th / TWO_PI_F) * (float)NMIN);
    m = m < 0 ? 0 : (m > NMIN - 1 ? NMIN - 1 : m);
    const float angle = (float)m * (TWO_PI_F / (float)(NMIN - 1));
    float c[FK], s[FK];
#pragma unroll
    for (int k = 0; k < FK; ++k) sincosf(angle * (float)(k + 1), &s[k], &c[k]);

    float4 acc[D / 4];
#pragma unroll
    for (int i = 0; i < D / 4; ++i) acc[i] = make_float4(0.f, 0.f, 0.f, 0.f);
#pragma unroll
    for (int n = 0; n < NC; ++n) {
        const float pw = sc[n];
#pragma unroll
        for (int i = 0; i < D / 4; ++i) {
            float4 v = sa04[n * (D / 4) + i];
#pragma unroll
            for (int k = 0; k < FK; ++k) {
                const float4 av = sfa4[(n * FK + k) * (D / 4) + i];
                const float4 bv = sfb4[(n * FK + k) * (D / 4) + i];
                v.x = fmaf(c[k], av.x, v.x); v.x = fmaf(s[k], bv.x, v.x);
                v.y = fmaf(c[k], av.y, v.y); v.y = fmaf(s[k], bv.y, v.y);
                v.z = fmaf(c[k], av.z, v.z); v.z = fmaf(s[k], bv.z, v.z);
                v.w = fmaf(c[k], av.w, v.w); v.w = fmaf(s[k], bv.w, v.w);
            }
            acc[i].x = fmaf(pw, v.x, acc[i].x);
            acc[i].y = fmaf(pw, v.y, acc[i].y);
            acc[i].z = fmaf(pw, v.z, acc[i].z);
            acc[i].w = fmaf(pw, v.w, acc[i].w);
        }
    }
    float4* o4 = (float4*)(out_emb + (size_t)b * D);
#pragma unroll
    for (int i = 0; i < D / 4; ++i) o4[i] = acc[i];
    float4* op = (float4*)(out_P + (size_t)b * NC);
    op[0] = make_float4(sc[0], sc[1], sc[2], sc[3]);
    op[1] = make_float4(sc[4], sc[5], sc[6], sc[7]);
}

extern "C" void kernel_launch(void* const* d_in, const int* in_sizes, int n_in,
                              void* d_out, int out_size, void* d_ws, size_t ws_size,
                              hipStream_t stream)
{
    const float* emb    = (const float*)d_in[0];
    const float* thetas = (const float*)d_in[1];
    const float* proto  = (const float*)d_in[2];
    const float* a0     = (const float*)d_in[3];
    const float* fa     = (const float*)d_in[4];
    const float* fb     = (const float*)d_in[5];

    const int B = in_sizes[0] / D;           // 131072
    float* out_emb = (float*)d_out;
    float* out_P   = (float*)d_out + (size_t)B * D;

    const size_t table_bytes = (size_t)NMIN * NC * D * sizeof(float); // ~2.95 MB

    if (ws_size >= table_bytes) {
        float* T = (float*)d_ws;
        build_table_kernel<<<NMIN, 256, 0, stream>>>(a0, fa, fb, T);
        // 16 lanes per item: B*16 threads total
        const long long total_threads = (long long)B * 16;
        const int blocks = (int)((total_threads + 255) / 256);
        mix_kernel16<<<blocks, 256, 0, stream>>>(emb, thetas, proto, T, out_emb, out_P, B);
    } else {
        const int blocks = (B + 255) / 256;
        fused_fallback<<<blocks, 256, 0, stream>>>(emb, thetas, proto, a0, fa, fb,
                                                   out_emb, out_P, B);
    }
}